// Round 1
// baseline (193.237 us; speedup 1.0000x reference)
//
#include <hip/hip_runtime.h>
#include <hip/hip_bf16.h>
#include <math.h>

#define BB 128
#define MM 200
#define SS 20
#define DD 128
#define NC 10000
#define CL 10
#define LCT 64  // logits cand-tile

__device__ __forceinline__ unsigned pack_bf16(float a, float b) {
    unsigned ua = __float_as_uint(a), ub = __float_as_uint(b);
    ua += 0x7fff + ((ua >> 16) & 1);  // RNE; inputs finite
    ub += 0x7fff + ((ub >> 16) & 1);
    return (ua >> 16) | (ub & 0xffff0000u);
}
__device__ __forceinline__ float bflo(unsigned v) { return __uint_as_float(v << 16); }
__device__ __forceinline__ float bfhi(unsigned v) { return __uint_as_float(v & 0xffff0000u); }

// Per-block index-width detection: odd 32-bit words of queries are the high
// halves iff indices are int64 (tokens < 2^32 -> all zero). For int32 they are
// real tokens (P(zero) = 1e-5 each). 8 broadcast loads, no extra dispatch.
__device__ __forceinline__ int detect_shift(const int* __restrict__ q) {
    int zc = 0;
#pragma unroll
    for (int i = 0; i < 8; ++i) zc += (q[2 * i + 1] == 0);
    return (zc >= 6) ? 1 : 0;
}

// A-table f32 -> packed bf16 (halves gather bytes for the story/query phase).
// Row 0 is written as zeros (padding_idx) so gathers need no mask.
__global__ __launch_bounds__(512) void k_conv(const float* __restrict__ A,
                                              unsigned* __restrict__ Abf) {
    size_t t = (size_t)blockIdx.x * 512 + threadIdx.x;  // 8 floats per thread
    const float4* in = (const float4*)(A + t * 8);
    float4 a = in[0], b = in[1];
    if (t * 8 < DD) {  // row 0
        a = make_float4(0.f, 0.f, 0.f, 0.f);
        b = make_float4(0.f, 0.f, 0.f, 0.f);
    }
    uint4 o;
    o.x = pack_bf16(a.x, a.y);
    o.y = pack_bf16(a.z, a.w);
    o.z = pack_bf16(b.x, b.y);
    o.w = pack_bf16(b.z, b.w);
    ((uint4*)(Abf + t * 4))[0] = o;
}

// Blocks 0..127: batch b — gather stories from bf16 A-table into LDS, gather
// u0, run 3 fused hops from LDS, write uT column.
// Blocks 128..752: candidate row-sums from f32 W (overlaps with the
// cache-BW-bound story gather on otherwise-idle CUs).
// LDS kept under 160K/3 = 54613 B (o_part eliminated; phase 2 folded into
// phase 3) -> 3 blocks/CU instead of 2: the gather phases are
// latency/concurrency-bound (VALUBusy 13%, HBM 23%, occupancy 18%), so
// resident-wave count is the lever. All 753 blocks co-resident in one shot.
__global__ __launch_bounds__(512) void k_main(const int* __restrict__ stories,
                                              const int* __restrict__ queries,
                                              const int* __restrict__ cands,
                                              const unsigned* __restrict__ Abf,
                                              const float* __restrict__ W,
                                              const float* __restrict__ Hw,
                                              float* __restrict__ uT,
                                              float* __restrict__ cand_buf) {
    __shared__ unsigned m_s[MM][DD / 2];  // packed bf16 pairs, 51.2 KB
    __shared__ float u_s[DD];
    __shared__ float p_s[MM];
    __shared__ float red_s;

    int bid = blockIdx.x;
    int tid = threadIdx.x;
    int shift = detect_shift(queries);

    if (bid < BB) {
        int b = bid;
        // ---- Story gather: 32 groups x 16 lanes; lane = uint4 (8 dims) of a
        //      bf16 row; 20 gathers in flight; no mask (row 0 pre-zeroed). ----
        int g = tid >> 4, l = tid & 15;
#pragma unroll
        for (int r = 0; r < 7; ++r) {
            int mm = g + (r << 5);
            if (mm < MM) {
                int toks[SS];
#pragma unroll
                for (int s = 0; s < SS; ++s)
                    toks[s] = stories[((size_t)((b * MM + mm) * SS + s)) << shift];
                float a[8] = {0.f, 0.f, 0.f, 0.f, 0.f, 0.f, 0.f, 0.f};
#pragma unroll
                for (int s = 0; s < SS; ++s) {
                    uint4 v = ((const uint4*)(Abf + (size_t)toks[s] * (DD / 2)))[l];
                    a[0] += bflo(v.x); a[1] += bfhi(v.x);
                    a[2] += bflo(v.y); a[3] += bfhi(v.y);
                    a[4] += bflo(v.z); a[5] += bfhi(v.z);
                    a[6] += bflo(v.w); a[7] += bfhi(v.w);
                }
                uint4 o;
                o.x = pack_bf16(a[0], a[1]);
                o.y = pack_bf16(a[2], a[3]);
                o.z = pack_bf16(a[4], a[5]);
                o.w = pack_bf16(a[6], a[7]);
                *(uint4*)&m_s[mm][4 * l] = o;
            }
        }
        // ---- u0[d] = sum_s Abf[q[b,s]][d] ----
        if (tid < DD) {
            int d = tid;
            float acc = 0.f;
#pragma unroll
            for (int s = 0; s < SS; ++s) {
                int tok = queries[((size_t)(b * SS + s)) << shift];
                unsigned pv = Abf[(size_t)tok * (DD / 2) + (d >> 1)];
                acc += (d & 1) ? bfhi(pv) : bflo(pv);
            }
            u_s[d] = acc;
        }
        __syncthreads();

        for (int hop = 0; hop < 3; ++hop) {
            // Phase 1: p[t] = m[t,:] . u — thread per row, rotated (conflict-free)
            if (tid < MM) {
                const float2* u2 = (const float2*)u_s;
                float acc = 0.f;
#pragma unroll 8
                for (int li = 0; li < 64; ++li) {
                    int j = (tid + li) & 63;
                    unsigned pv = m_s[tid][j];
                    float2 uv = u2[j];
                    acc += bflo(pv) * uv.x + bfhi(pv) * uv.y;
                }
                p_s[tid] = acc;
            }
            __syncthreads();
            // Softmax over 200 (wave 0; 1/sum deferred to fused phase)
            if (tid < 64) {
                float v0 = p_s[tid], v1 = p_s[tid + 64], v2 = p_s[tid + 128];
                float v3 = (tid < 8) ? p_s[tid + 192] : -1e30f;
                float mx = fmaxf(fmaxf(v0, v1), fmaxf(v2, v3));
                for (int off = 32; off; off >>= 1) mx = fmaxf(mx, __shfl_down(mx, off));
                mx = __shfl(mx, 0);
                float e0 = __expf(v0 - mx), e1 = __expf(v1 - mx), e2 = __expf(v2 - mx);
                float e3 = (tid < 8) ? __expf(v3 - mx) : 0.f;
                float sm = e0 + e1 + e2 + e3;
                for (int off = 32; off; off >>= 1) sm += __shfl_down(sm, off);
                p_s[tid] = e0;
                p_s[tid + 64] = e1;
                p_s[tid + 128] = e2;
                if (tid < 8) p_s[tid + 192] = e3;
                if (tid == 0) red_s = 1.f / __shfl(sm, 0);
            }
            __syncthreads();
            // Phase 2+3 fused: u'[d] = tanh( Hw[d,:].u + red * sum_k e[k]*m[k,d] )
            // Per-d serial 200-row sum: m_s[k][d>>1] is a 2-lane broadcast,
            // banks 0..31 conflict-free per wave; p_s[k] is full broadcast.
            // 4 accumulators break the FMA dependence chain. This replaces the
            // 512-thread o_part reduction: costs ~1 us/hop serial per block but
            // frees 4 KB LDS (-> 3 blocks/CU) and one barrier per hop.
            float u_new = 0.f;
            if (tid < DD) {
                int d = tid;
                int w = d >> 1;
                float a0 = 0.f, a1 = 0.f, a2 = 0.f, a3 = 0.f;
                for (int k = 0; k < MM; k += 4) {
                    unsigned w0 = m_s[k][w];
                    unsigned w1 = m_s[k + 1][w];
                    unsigned w2 = m_s[k + 2][w];
                    unsigned w3 = m_s[k + 3][w];
                    float m0 = (d & 1) ? bfhi(w0) : bflo(w0);
                    float m1 = (d & 1) ? bfhi(w1) : bflo(w1);
                    float m2 = (d & 1) ? bfhi(w2) : bflo(w2);
                    float m3 = (d & 1) ? bfhi(w3) : bflo(w3);
                    a0 = fmaf(p_s[k], m0, a0);
                    a1 = fmaf(p_s[k + 1], m1, a1);
                    a2 = fmaf(p_s[k + 2], m2, a2);
                    a3 = fmaf(p_s[k + 3], m3, a3);
                }
                float acc = ((a0 + a1) + (a2 + a3)) * red_s;
                const float4* hrow = (const float4*)(Hw + d * DD);
                const float4* u4 = (const float4*)u_s;
#pragma unroll 8
                for (int j = 0; j < DD / 4; ++j) {
                    float4 hv = hrow[j];
                    float4 uv = u4[j];
                    acc += hv.x * uv.x + hv.y * uv.y + hv.z * uv.z + hv.w * uv.w;
                }
                u_new = tanhf(acc);
            }
            __syncthreads();
            if (tid < DD) u_s[tid] = u_new;
            __syncthreads();
        }
        if (tid < DD) uT[tid * BB + bid] = u_s[tid];
    } else {
        // ---- Candidate row-sums from f32 W (masked; W row 0 not zeroed) ----
        int g = tid >> 5, l = tid & 31;
        int row = (bid - BB) * 16 + g;
        int toks[CL];
#pragma unroll
        for (int s = 0; s < CL; ++s)
            toks[s] = cands[((size_t)(row * CL + s)) << shift];
        float4 acc = make_float4(0.f, 0.f, 0.f, 0.f);
#pragma unroll
        for (int s = 0; s < CL; ++s) {
            float4 v = ((const float4*)(W + (size_t)toks[s] * DD))[l];
            float msk = toks[s] ? 1.f : 0.f;
            acc.x = fmaf(msk, v.x, acc.x);
            acc.y = fmaf(msk, v.y, acc.y);
            acc.z = fmaf(msk, v.z, acc.z);
            acc.w = fmaf(msk, v.w, acc.w);
        }
        ((float4*)(cand_buf + (size_t)row * DD))[l] = acc;
    }
}

// logits[b,c] = u[b,:] . cand_sum[c,:]. Block = 128 batches x 64 cands,
// 256 threads; thread = 4-batch x 8-cand register tile. Cand tile transposed
// to k-major in LDS (pad 68) so the inner loop is 2 b128 LDS + 1 float4
// global per 4 k's per thread.
__global__ __launch_bounds__(256) void k_logits(const float* __restrict__ uT,
                                                const float* __restrict__ cs,
                                                float* __restrict__ out) {
    __shared__ float c_s[DD][LCT + 4];  // [k][c], 34.8 KB
    int c0 = blockIdx.x * LCT;
    int tid = threadIdx.x;
    {
        int c = tid >> 2, l = tid & 3;  // c 0..63, l = k-quarter
        int row = c0 + c;
        if (row >= NC) row = NC - 1;
        const float4* rp = (const float4*)(cs + (size_t)row * DD);
#pragma unroll
        for (int i = 0; i < 8; ++i) {
            int k = (l << 5) + (i << 2);
            float4 v = rp[(l << 3) + i];
            c_s[k][c] = v.x;
            c_s[k + 1][c] = v.y;
            c_s[k + 2][c] = v.z;
            c_s[k + 3][c] = v.w;
        }
    }
    __syncthreads();
    int tx = tid & 31, ty = tid >> 5;  // tx: 4 batches, ty: 8 cands
    const float* cb = &c_s[0][ty << 3];
    const float4* up = (const float4*)(uT + (tx << 2));
    float acc[4][8];
#pragma unroll
    for (int i = 0; i < 4; ++i)
#pragma unroll
        for (int j = 0; j < 8; ++j) acc[i][j] = 0.f;
#pragma unroll 4
    for (int k = 0; k < DD; ++k) {
        float4 uv = up[k * (BB / 4)];
        float4 ca = *(const float4*)(cb + k * (LCT + 4));
        float4 cc = *(const float4*)(cb + k * (LCT + 4) + 4);
        float uu[4] = {uv.x, uv.y, uv.z, uv.w};
        float cv[8] = {ca.x, ca.y, ca.z, ca.w, cc.x, cc.y, cc.z, cc.w};
#pragma unroll
        for (int i = 0; i < 4; ++i)
#pragma unroll
            for (int j = 0; j < 8; ++j) acc[i][j] = fmaf(uu[i], cv[j], acc[i][j]);
    }
    if (c0 + (ty << 3) < NC) {  // NC % 8 == 0 -> whole 8-chunk valid
#pragma unroll
        for (int i = 0; i < 4; ++i) {
            float* orow = out + (size_t)((tx << 2) + i) * NC + c0 + (ty << 3);
            ((float4*)orow)[0] = make_float4(acc[i][0], acc[i][1], acc[i][2], acc[i][3]);
            ((float4*)orow)[1] = make_float4(acc[i][4], acc[i][5], acc[i][6], acc[i][7]);
        }
    }
}

extern "C" void kernel_launch(void* const* d_in, const int* in_sizes, int n_in,
                              void* d_out, int out_size, void* d_ws, size_t ws_size,
                              hipStream_t stream) {
    const int* stories = (const int*)d_in[0];       // [128,200,20] tokens
    const int* queries = (const int*)d_in[1];       // [128,20]
    const int* cands   = (const int*)d_in[2];       // [10000,10]
    const float* A  = (const float*)d_in[3];        // f32 [100000,128]
    const float* W  = (const float*)d_in[4];        // f32 [100000,128]
    const float* Hw = (const float*)d_in[5];        // f32 [128,128]
    float* out = (float*)d_out;                     // f32 [128,10000]

    unsigned* Abf = (unsigned*)d_ws;                 // 100000*64 uints = 25.6 MB
    float* cand_buf = (float*)(Abf + 100000 * (DD / 2));  // 5.12 MB
    float* uT_buf = cand_buf + (size_t)NC * DD;      // 64 KB  (total ~30.8 MB)

    k_conv<<<100000 * DD / 8 / 512, 512, 0, stream>>>(A, Abf);
    k_main<<<BB + NC / 16, 512, 0, stream>>>(stories, queries, cands, Abf, W, Hw,
                                             uT_buf, cand_buf);
    k_logits<<<(NC + LCT - 1) / LCT, 256, 0, stream>>>(uT_buf, cand_buf, out);
}

// Round 2
// 185.434 us; speedup vs baseline: 1.0421x; 1.0421x over previous
//
#include <hip/hip_runtime.h>
#include <hip/hip_bf16.h>
#include <math.h>

#define BB 128
#define MM 200
#define SS 20
#define DD 128
#define NC 10000
#define CL 10
#define LCT 64  // logits cand-tile

__device__ __forceinline__ unsigned pack_bf16(float a, float b) {
    unsigned ua = __float_as_uint(a), ub = __float_as_uint(b);
    ua += 0x7fff + ((ua >> 16) & 1);  // RNE; inputs finite
    ub += 0x7fff + ((ub >> 16) & 1);
    return (ua >> 16) | (ub & 0xffff0000u);
}
__device__ __forceinline__ float bflo(unsigned v) { return __uint_as_float(v << 16); }
__device__ __forceinline__ float bfhi(unsigned v) { return __uint_as_float(v & 0xffff0000u); }

// Per-block index-width detection: odd 32-bit words of queries are the high
// halves iff indices are int64 (tokens < 2^32 -> all zero). For int32 they are
// real tokens (P(zero) = 1e-5 each). 8 broadcast loads, no extra dispatch.
__device__ __forceinline__ int detect_shift(const int* __restrict__ q) {
    int zc = 0;
#pragma unroll
    for (int i = 0; i < 8; ++i) zc += (q[2 * i + 1] == 0);
    return (zc >= 6) ? 1 : 0;
}

// A-table f32 -> packed bf16 (halves gather bytes for the story/query phase).
// Row 0 is written as zeros (padding_idx) so gathers need no mask.
__global__ __launch_bounds__(512) void k_conv(const float* __restrict__ A,
                                              unsigned* __restrict__ Abf) {
    size_t t = (size_t)blockIdx.x * 512 + threadIdx.x;  // 8 floats per thread
    const float4* in = (const float4*)(A + t * 8);
    float4 a = in[0], b = in[1];
    if (t * 8 < DD) {  // row 0
        a = make_float4(0.f, 0.f, 0.f, 0.f);
        b = make_float4(0.f, 0.f, 0.f, 0.f);
    }
    uint4 o;
    o.x = pack_bf16(a.x, a.y);
    o.y = pack_bf16(a.z, a.w);
    o.z = pack_bf16(b.x, b.y);
    o.w = pack_bf16(b.z, b.w);
    ((uint4*)(Abf + t * 4))[0] = o;
}

// Blocks 0..127: batch b — gather stories from bf16 A-table into LDS, gather
// u0, run 3 fused hops from LDS, write uT column.
// Blocks 128..752: candidate row-sums from f32 W (overlaps with the
// latency-bound story gather on otherwise-idle CUs).
// Gathers are explicitly STAGED into registers (vb[]) before accumulation:
// round-0 profile showed VGPR=52 -> only ~2-3 gathers in flight per wave,
// VALUBusy 13% / HBM 23% / all pipes idle = load-latency-bound. Staging all
// 20 (stories) / 10 (cands) row-gathers batches the latency.
// __launch_bounds__(512,4) caps VGPR at 128 (4 waves/SIMD, 2 blocks/CU).
__global__ __launch_bounds__(512, 4) void k_main(const int* __restrict__ stories,
                                                 const int* __restrict__ queries,
                                                 const int* __restrict__ cands,
                                                 const unsigned* __restrict__ Abf,
                                                 const float* __restrict__ W,
                                                 const float* __restrict__ Hw,
                                                 float* __restrict__ uT,
                                                 float* __restrict__ cand_buf) {
    __shared__ unsigned m_s[MM][DD / 2];  // packed bf16 pairs, 51.2 KB
    __shared__ float u_s[DD];
    __shared__ float p_s[MM];
    __shared__ float o_part[8][DD];
    __shared__ float red_s;

    int bid = blockIdx.x;
    int tid = threadIdx.x;
    int shift = detect_shift(queries);

    if (bid < BB) {
        int b = bid;
        // ---- Story gather: 32 groups x 16 lanes; lane = uint4 (8 dims) of a
        //      bf16 row; all 20 gathers staged -> in flight simultaneously;
        //      no mask (row 0 pre-zeroed). ----
        int g = tid >> 4, l = tid & 15;
#pragma unroll
        for (int r = 0; r < 7; ++r) {
            int mm = g + (r << 5);
            if (mm < MM) {
                int toks[SS];
#pragma unroll
                for (int s = 0; s < SS; ++s)
                    toks[s] = stories[((size_t)((b * MM + mm) * SS + s)) << shift];
                uint4 vb[SS];
#pragma unroll
                for (int s = 0; s < SS; ++s)
                    vb[s] = ((const uint4*)(Abf + ((size_t)(unsigned)toks[s] << 6)))[l];
                float a[8] = {0.f, 0.f, 0.f, 0.f, 0.f, 0.f, 0.f, 0.f};
#pragma unroll
                for (int s = 0; s < SS; ++s) {
                    uint4 v = vb[s];
                    a[0] += bflo(v.x); a[1] += bfhi(v.x);
                    a[2] += bflo(v.y); a[3] += bfhi(v.y);
                    a[4] += bflo(v.z); a[5] += bfhi(v.z);
                    a[6] += bflo(v.w); a[7] += bfhi(v.w);
                }
                uint4 o;
                o.x = pack_bf16(a[0], a[1]);
                o.y = pack_bf16(a[2], a[3]);
                o.z = pack_bf16(a[4], a[5]);
                o.w = pack_bf16(a[6], a[7]);
                *(uint4*)&m_s[mm][4 * l] = o;
            }
        }
        // ---- u0[d] = sum_s Abf[q[b,s]][d] ----
        if (tid < DD) {
            int d = tid;
            int qt[SS];
#pragma unroll
            for (int s = 0; s < SS; ++s)
                qt[s] = queries[((size_t)(b * SS + s)) << shift];
            unsigned pv[SS];
#pragma unroll
            for (int s = 0; s < SS; ++s)
                pv[s] = Abf[((size_t)(unsigned)qt[s] << 6) + (d >> 1)];
            float acc = 0.f;
#pragma unroll
            for (int s = 0; s < SS; ++s)
                acc += (d & 1) ? bfhi(pv[s]) : bflo(pv[s]);
            u_s[d] = acc;
        }
        __syncthreads();

        for (int hop = 0; hop < 3; ++hop) {
            // Phase 1: p[t] = m[t,:] . u — thread per row, rotated (conflict-free)
            if (tid < MM) {
                const float2* u2 = (const float2*)u_s;
                float acc = 0.f;
#pragma unroll 8
                for (int li = 0; li < 64; ++li) {
                    int j = (tid + li) & 63;
                    unsigned pv = m_s[tid][j];
                    float2 uv = u2[j];
                    acc += bflo(pv) * uv.x + bfhi(pv) * uv.y;
                }
                p_s[tid] = acc;
            }
            __syncthreads();
            // Softmax over 200 (wave 0; 1/sum deferred to phase 3)
            if (tid < 64) {
                float v0 = p_s[tid], v1 = p_s[tid + 64], v2 = p_s[tid + 128];
                float v3 = (tid < 8) ? p_s[tid + 192] : -1e30f;
                float mx = fmaxf(fmaxf(v0, v1), fmaxf(v2, v3));
                for (int off = 32; off; off >>= 1) mx = fmaxf(mx, __shfl_down(mx, off));
                mx = __shfl(mx, 0);
                float e0 = __expf(v0 - mx), e1 = __expf(v1 - mx), e2 = __expf(v2 - mx);
                float e3 = (tid < 8) ? __expf(v3 - mx) : 0.f;
                float sm = e0 + e1 + e2 + e3;
                for (int off = 32; off; off >>= 1) sm += __shfl_down(sm, off);
                p_s[tid] = e0;
                p_s[tid + 64] = e1;
                p_s[tid + 128] = e2;
                if (tid < 8) p_s[tid + 192] = e3;
                if (tid == 0) red_s = 1.f / __shfl(sm, 0);
            }
            __syncthreads();
            // Phase 2: o[d] = sum_mm e[mm]*m[mm,d], mm split 8 ways
            {
                int c = tid & 63, h = tid >> 6;
                int mm0 = h * 25;
                float ax = 0.f, ay = 0.f;
#pragma unroll 5
                for (int k = 0; k < 25; ++k) {
                    unsigned pv = m_s[mm0 + k][c];
                    float p = p_s[mm0 + k];
                    ax = fmaf(p, bflo(pv), ax);
                    ay = fmaf(p, bfhi(pv), ay);
                }
                o_part[h][2 * c] = ax;
                o_part[h][2 * c + 1] = ay;
            }
            __syncthreads();
            // Phase 3: u'[d] = tanh( Hw[d,:] . u + inv * o[d] )
            float u_new = 0.f;
            if (tid < DD) {
                float o = 0.f;
#pragma unroll
                for (int h = 0; h < 8; ++h) o += o_part[h][tid];
                float acc = o * red_s;
                const float4* hrow = (const float4*)(Hw + tid * DD);
                const float4* u4 = (const float4*)u_s;
#pragma unroll 8
                for (int j = 0; j < DD / 4; ++j) {
                    float4 hv = hrow[j];
                    float4 uv = u4[j];
                    acc += hv.x * uv.x + hv.y * uv.y + hv.z * uv.z + hv.w * uv.w;
                }
                u_new = tanhf(acc);
            }
            __syncthreads();
            if (tid < DD) u_s[tid] = u_new;
            __syncthreads();
        }
        if (tid < DD) uT[tid * BB + bid] = u_s[tid];
    } else {
        // ---- Candidate row-sums from f32 W (masked; W row 0 not zeroed);
        //      all 10 row-gathers staged. ----
        int g = tid >> 5, l = tid & 31;
        int row = (bid - BB) * 16 + g;
        int toks[CL];
#pragma unroll
        for (int s = 0; s < CL; ++s)
            toks[s] = cands[((size_t)(row * CL + s)) << shift];
        float4 vb[CL];
#pragma unroll
        for (int s = 0; s < CL; ++s)
            vb[s] = ((const float4*)(W + (size_t)(unsigned)toks[s] * DD))[l];
        float4 acc = make_float4(0.f, 0.f, 0.f, 0.f);
#pragma unroll
        for (int s = 0; s < CL; ++s) {
            float msk = toks[s] ? 1.f : 0.f;
            acc.x = fmaf(msk, vb[s].x, acc.x);
            acc.y = fmaf(msk, vb[s].y, acc.y);
            acc.z = fmaf(msk, vb[s].z, acc.z);
            acc.w = fmaf(msk, vb[s].w, acc.w);
        }
        ((float4*)(cand_buf + (size_t)row * DD))[l] = acc;
    }
}

// logits[b,c] = u[b,:] . cand_sum[c,:]. Block = 128 batches x 64 cands,
// 256 threads; thread = 4-batch x 8-cand register tile. Cand tile transposed
// to k-major in LDS (pad 68) so the inner loop is 2 b128 LDS + 1 float4
// global per 4 k's per thread.
__global__ __launch_bounds__(256) void k_logits(const float* __restrict__ uT,
                                                const float* __restrict__ cs,
                                                float* __restrict__ out) {
    __shared__ float c_s[DD][LCT + 4];  // [k][c], 34.8 KB
    int c0 = blockIdx.x * LCT;
    int tid = threadIdx.x;
    {
        int c = tid >> 2, l = tid & 3;  // c 0..63, l = k-quarter
        int row = c0 + c;
        if (row >= NC) row = NC - 1;
        const float4* rp = (const float4*)(cs + (size_t)row * DD);
#pragma unroll
        for (int i = 0; i < 8; ++i) {
            int k = (l << 5) + (i << 2);
            float4 v = rp[(l << 3) + i];
            c_s[k][c] = v.x;
            c_s[k + 1][c] = v.y;
            c_s[k + 2][c] = v.z;
            c_s[k + 3][c] = v.w;
        }
    }
    __syncthreads();
    int tx = tid & 31, ty = tid >> 5;  // tx: 4 batches, ty: 8 cands
    const float* cb = &c_s[0][ty << 3];
    const float4* up = (const float4*)(uT + (tx << 2));
    float acc[4][8];
#pragma unroll
    for (int i = 0; i < 4; ++i)
#pragma unroll
        for (int j = 0; j < 8; ++j) acc[i][j] = 0.f;
#pragma unroll 4
    for (int k = 0; k < DD; ++k) {
        float4 uv = up[k * (BB / 4)];
        float4 ca = *(const float4*)(cb + k * (LCT + 4));
        float4 cc = *(const float4*)(cb + k * (LCT + 4) + 4);
        float uu[4] = {uv.x, uv.y, uv.z, uv.w};
        float cv[8] = {ca.x, ca.y, ca.z, ca.w, cc.x, cc.y, cc.z, cc.w};
#pragma unroll
        for (int i = 0; i < 4; ++i)
#pragma unroll
            for (int j = 0; j < 8; ++j) acc[i][j] = fmaf(uu[i], cv[j], acc[i][j]);
    }
    if (c0 + (ty << 3) < NC) {  // NC % 8 == 0 -> whole 8-chunk valid
#pragma unroll
        for (int i = 0; i < 4; ++i) {
            float* orow = out + (size_t)((tx << 2) + i) * NC + c0 + (ty << 3);
            ((float4*)orow)[0] = make_float4(acc[i][0], acc[i][1], acc[i][2], acc[i][3]);
            ((float4*)orow)[1] = make_float4(acc[i][4], acc[i][5], acc[i][6], acc[i][7]);
        }
    }
}

extern "C" void kernel_launch(void* const* d_in, const int* in_sizes, int n_in,
                              void* d_out, int out_size, void* d_ws, size_t ws_size,
                              hipStream_t stream) {
    const int* stories = (const int*)d_in[0];       // [128,200,20] tokens
    const int* queries = (const int*)d_in[1];       // [128,20]
    const int* cands   = (const int*)d_in[2];       // [10000,10]
    const float* A  = (const float*)d_in[3];        // f32 [100000,128]
    const float* W  = (const float*)d_in[4];        // f32 [100000,128]
    const float* Hw = (const float*)d_in[5];        // f32 [128,128]
    float* out = (float*)d_out;                     // f32 [128,10000]

    unsigned* Abf = (unsigned*)d_ws;                 // 100000*64 uints = 25.6 MB
    float* cand_buf = (float*)(Abf + 100000 * (DD / 2));  // 5.12 MB
    float* uT_buf = cand_buf + (size_t)NC * DD;      // 64 KB  (total ~30.8 MB)

    k_conv<<<100000 * DD / 8 / 512, 512, 0, stream>>>(A, Abf);
    k_main<<<BB + NC / 16, 512, 0, stream>>>(stories, queries, cands, Abf, W, Hw,
                                             uT_buf, cand_buf);
    k_logits<<<(NC + LCT - 1) / LCT, 256, 0, stream>>>(uT_buf, cand_buf, out);
}